// Round 2
// baseline (507.372 us; speedup 1.0000x reference)
//
#include <hip/hip_runtime.h>
#include <math.h>

constexpr int NB = 8;
constexpr int NC = 256;
constexpr int NCR = 64;
constexpr int NH = 160;
constexpr int NW = 160;
constexpr int NHW = NH * NW;           // 25600
constexpr float KEPS = 1e-4f;

constexpr int TW = 32;                 // tile width
constexpr int TH = 8;                  // tile height

// K0: transpose rw[d][c] -> rwT[c][d]; block 0 also zeroes pooledsum
__global__ __launch_bounds__(256) void k_tr(const float* __restrict__ rw,
                                            float* __restrict__ rwT,
                                            float* __restrict__ pooledsum) {
    const int i = blockIdx.x * 256 + threadIdx.x;    // over 16384
    const int d = i >> 8, c = i & 255;
    rwT[c * NCR + d] = rw[i];
    if (blockIdx.x == 0) {
        pooledsum[threadIdx.x] = 0.f;
        pooledsum[256 + threadIdx.x] = 0.f;
    }
}

// K1: y[b,d,p] = sum_c x[b,c,p] * rwT[c][d]; also accumulates pooled sums.
// Block: 128 pixels x 2 d-groups (32 d each). 32 accumulators/thread.
__global__ __launch_bounds__(256) void k_reduce(const float* __restrict__ x,
                                                const float* __restrict__ rwT,
                                                float* __restrict__ y,
                                                float* __restrict__ pooledsum) {
    const int t = threadIdx.x;
    const int pix = t & 127;                         // 0..127
    const int dg = __builtin_amdgcn_readfirstlane(t >> 7);  // wave-uniform 0/1
    const int blocksPerImg = NHW / 128;              // 200
    const int b = blockIdx.x / blocksPerImg;
    const int p = (blockIdx.x % blocksPerImg) * 128 + pix;

    const float* xb = x + (size_t)b * NC * NHW + p;
    const float* wt = rwT + dg * 32;

    float acc[32];
#pragma unroll
    for (int j = 0; j < 32; ++j) acc[j] = 0.f;

#pragma unroll 2
    for (int c = 0; c < NC; ++c) {
        const float v = xb[(size_t)c * NHW];
        const float* w = wt + c * NCR;
#pragma unroll
        for (int j = 0; j < 32; ++j) acc[j] = fmaf(v, w[j], acc[j]);
    }

    float* yb = y + (size_t)b * NCR * NHW + (size_t)(dg * 32) * NHW + p;
#pragma unroll
    for (int j = 0; j < 32; ++j) yb[(size_t)j * NHW] = acc[j];

    // pooled partial sums: reduce each acc[j] across the 64-lane wave
    const int lane = t & 63;
    float* ps = pooledsum + b * NCR + dg * 32;
#pragma unroll
    for (int j = 0; j < 32; ++j) {
        float s = acc[j];
#pragma unroll
        for (int o = 32; o > 0; o >>= 1) s += __shfl_down(s, o, 64);
        if (lane == 0) atomicAdd(&ps[j], s);
    }
}

// K2: gamma[b,d] = sigmoid(relu(mean@w1^T+b1)@w2^T+b2); pooledsum -> mean
__global__ __launch_bounds__(512) void k_gate(const float* __restrict__ pooledsum,
                                              const float* __restrict__ w1,
                                              const float* __restrict__ b1,
                                              const float* __restrict__ w2,
                                              const float* __restrict__ b2,
                                              float* __restrict__ gamma) {
    __shared__ float hsh[NB][16];
    const int t = threadIdx.x;
    constexpr float inv = 1.f / (float)NHW;
    if (t < NB * 16) {
        const int b = t / 16, j = t % 16;
        float s = b1[j];
        for (int d = 0; d < NCR; ++d)
            s = fmaf(pooledsum[b * NCR + d] * inv, w1[j * NCR + d], s);
        hsh[b][j] = fmaxf(s, 0.f);
    }
    __syncthreads();
    const int b = t / NCR, d = t % NCR;
    float s = b2[d];
#pragma unroll
    for (int j = 0; j < 16; ++j) s = fmaf(hsh[b][j], w2[d * 16 + j], s);
    gamma[t] = 1.f / (1.f + expf(-s));
}

// K3: per (b, 32x8 tile): stencil on y -> kappa -> logits -> a; out = x*(1+a)
__global__ __launch_bounds__(256) void k_fuse(const float* __restrict__ x,
                                              const float* __restrict__ y,
                                              const float* __restrict__ gamma,
                                              const float* __restrict__ fw,
                                              float* __restrict__ out) {
    __shared__ float tile[TH + 2][TW + 2];           // 10 x 34
    __shared__ float coef[NCR];
    __shared__ float sm[TH][TW];                     // 1+a per pixel

    const int b = blockIdx.z;
    const int w0 = blockIdx.x * TW, h0 = blockIdx.y * TH;
    const int t = threadIdx.x;
    const int tx = t % TW, ty = t / TW;

    if (t < NCR) coef[t] = fw[t] + gamma[b * NCR + t] * fw[NCR + t];
    __syncthreads();

    const float* yb = y + (size_t)b * NCR * NHW;
    float logit = 0.f;

    for (int c = 0; c < NCR; ++c) {
        const float* yc = yb + (size_t)c * NHW;
        for (int i = t; i < (TH + 2) * (TW + 2); i += 256) {
            const int iy = i / (TW + 2), ix = i % (TW + 2);
            const int gh = h0 + iy - 1, gw = w0 + ix - 1;
            float v = 0.f;
            if (gh >= 0 && gh < NH && gw >= 0 && gw < NW) v = yc[gh * NW + gw];
            tile[iy][ix] = v;
        }
        __syncthreads();

        const float a00 = tile[ty][tx],     a01 = tile[ty][tx + 1],     a02 = tile[ty][tx + 2];
        const float a10 = tile[ty + 1][tx], a11 = tile[ty + 1][tx + 1], a12 = tile[ty + 1][tx + 2];
        const float a20 = tile[ty + 2][tx], a21 = tile[ty + 2][tx + 1], a22 = tile[ty + 2][tx + 2];

        const float mu = (a00 + a01 + a02 + a10 + a11 + a12 + a20 + a21 + a22) * (1.f / 9.f);
        const float gx = (a00 - a02 + 2.f * (a10 - a12) + a20 - a22) * 0.125f;
        const float gy = (a00 + 2.f * a01 + a02 - a20 - 2.f * a21 - a22) * 0.125f;
        const float kappa = 1.f - fabsf(a11 - mu) / (fabsf(gx) + fabsf(gy) + KEPS);
        logit = fmaf(kappa, coef[c], logit);
        __syncthreads();
    }

    const float a = 1.f / (1.f + expf(-logit));
    sm[ty][tx] = 1.f + a;
    __syncthreads();

    // streaming multiply: remap threads to 4-wide float4 spans, 4 channel-groups
    const int cg = t >> 6;                           // 0..3
    const int rr = (t >> 3) & 7;                     // row 0..7
    const int cw = (t & 7) * 4;                      // col 0,4,...,28
    const float4 m4 = *reinterpret_cast<const float4*>(&sm[rr][cw]);

    const size_t base = (size_t)b * NC * NHW + (size_t)cg * NHW + (h0 + rr) * NW + (w0 + cw);
    const float* xp = x + base;
    float* op = out + base;
    const size_t stride = (size_t)4 * NHW;

#pragma unroll 4
    for (int it = 0; it < NC / 4; ++it) {
        float4 v = *reinterpret_cast<const float4*>(xp);
        float4 r;
        r.x = v.x * m4.x; r.y = v.y * m4.y; r.z = v.z * m4.z; r.w = v.w * m4.w;
        *reinterpret_cast<float4*>(op) = r;
        xp += stride; op += stride;
    }
}

extern "C" void kernel_launch(void* const* d_in, const int* in_sizes, int n_in,
                              void* d_out, int out_size, void* d_ws, size_t ws_size,
                              hipStream_t stream) {
    const float* x  = (const float*)d_in[0];
    const float* rw = (const float*)d_in[1];
    const float* w1 = (const float*)d_in[2];
    const float* b1 = (const float*)d_in[3];
    const float* w2 = (const float*)d_in[4];
    const float* b2 = (const float*)d_in[5];
    const float* fw = (const float*)d_in[6];
    float* out = (float*)d_out;

    float* y      = (float*)d_ws;                       // 13,107,200 floats
    float* pooled = y + (size_t)NB * NCR * NHW;         // 512 floats (sums)
    float* gamma  = pooled + NB * NCR;                  // 512 floats
    float* rwT    = gamma + NB * NCR;                   // 16384 floats

    k_tr<<<dim3(64), 256, 0, stream>>>(rw, rwT, pooled);
    k_reduce<<<dim3(NB * (NHW / 128)), 256, 0, stream>>>(x, rwT, y, pooled);
    k_gate<<<dim3(1), 512, 0, stream>>>(pooled, w1, b1, w2, b2, gamma);
    k_fuse<<<dim3(NW / TW, NH / TH, NB), 256, 0, stream>>>(x, y, gamma, fw, out);
}

// Round 3
// 491.246 us; speedup vs baseline: 1.0328x; 1.0328x over previous
//
#include <hip/hip_runtime.h>
#include <math.h>

constexpr int NB = 8;
constexpr int NC = 256;
constexpr int NCR = 64;
constexpr int NH = 160;
constexpr int NW = 160;
constexpr int NHW = NH * NW;           // 25600
constexpr float KEPS = 1e-4f;

constexpr int TW = 32;                 // tile width
constexpr int TH = 8;                  // tile height

// K0: transpose rw[d][c] -> rwT[c][d]; block 0 also zeroes pooledsum
__global__ __launch_bounds__(256) void k_tr(const float* __restrict__ rw,
                                            float* __restrict__ rwT,
                                            float* __restrict__ pooledsum) {
    const int i = blockIdx.x * 256 + threadIdx.x;    // over 16384
    const int d = i >> 8, c = i & 255;
    rwT[c * NCR + d] = rw[i];
    if (blockIdx.x == 0) {
        pooledsum[threadIdx.x] = 0.f;
        pooledsum[256 + threadIdx.x] = 0.f;
    }
}

// K1: y[b,d,p] = sum_c x[b,c,p] * rwT[c][d]; also accumulates pooled sums.
// One pixel per thread, all 64 outputs per thread (64 VGPR accumulators).
// Weights are wave-uniform -> scalar loads (s_load_dwordx16), co-issued with FMAs.
// launch_bounds(256, 2): min 2 waves/EU -> VGPR cap 256 -> NO SPILL.
__global__ __launch_bounds__(256, 2) void k_reduce(const float* __restrict__ x,
                                                   const float* __restrict__ rwT,
                                                   float* __restrict__ y,
                                                   float* __restrict__ pooledsum) {
    const int t = threadIdx.x;
    const int blocksPerImg = NHW / 256;              // 100
    const int b = blockIdx.x / blocksPerImg;
    const int p = (blockIdx.x % blocksPerImg) * 256 + t;

    const float* xb = x + (size_t)b * NC * NHW + p;

    float acc[NCR];
#pragma unroll
    for (int j = 0; j < NCR; ++j) acc[j] = 0.f;

    for (int c0 = 0; c0 < NC; c0 += 4) {
        // 4 x-values in flight to hide VMEM latency under the 256 FMAs
        float v0 = xb[(size_t)(c0 + 0) * NHW];
        float v1 = xb[(size_t)(c0 + 1) * NHW];
        float v2 = xb[(size_t)(c0 + 2) * NHW];
        float v3 = xb[(size_t)(c0 + 3) * NHW];
        const float* w0 = rwT + (c0 + 0) * NCR;
        const float* w1 = rwT + (c0 + 1) * NCR;
        const float* w2 = rwT + (c0 + 2) * NCR;
        const float* w3 = rwT + (c0 + 3) * NCR;
#pragma unroll
        for (int j = 0; j < NCR; ++j) acc[j] = fmaf(v0, w0[j], acc[j]);
#pragma unroll
        for (int j = 0; j < NCR; ++j) acc[j] = fmaf(v1, w1[j], acc[j]);
#pragma unroll
        for (int j = 0; j < NCR; ++j) acc[j] = fmaf(v2, w2[j], acc[j]);
#pragma unroll
        for (int j = 0; j < NCR; ++j) acc[j] = fmaf(v3, w3[j], acc[j]);
    }

    float* yb = y + (size_t)b * NCR * NHW + p;
#pragma unroll
    for (int j = 0; j < NCR; ++j) yb[(size_t)j * NHW] = acc[j];

    // pooled partial sums: reduce each acc[j] across the 64-lane wave
    const int lane = t & 63;
    float* ps = pooledsum + b * NCR;
#pragma unroll
    for (int j = 0; j < NCR; ++j) {
        float s = acc[j];
#pragma unroll
        for (int o = 32; o > 0; o >>= 1) s += __shfl_down(s, o, 64);
        if (lane == 0) atomicAdd(&ps[j], s);
    }
}

// K2: gamma[b,d] = sigmoid(relu(mean@w1^T+b1)@w2^T+b2); pooledsum -> mean
__global__ __launch_bounds__(512) void k_gate(const float* __restrict__ pooledsum,
                                              const float* __restrict__ w1,
                                              const float* __restrict__ b1,
                                              const float* __restrict__ w2,
                                              const float* __restrict__ b2,
                                              float* __restrict__ gamma) {
    __shared__ float hsh[NB][16];
    const int t = threadIdx.x;
    constexpr float inv = 1.f / (float)NHW;
    if (t < NB * 16) {
        const int b = t / 16, j = t % 16;
        float s = b1[j];
        for (int d = 0; d < NCR; ++d)
            s = fmaf(pooledsum[b * NCR + d] * inv, w1[j * NCR + d], s);
        hsh[b][j] = fmaxf(s, 0.f);
    }
    __syncthreads();
    const int b = t / NCR, d = t % NCR;
    float s = b2[d];
#pragma unroll
    for (int j = 0; j < 16; ++j) s = fmaf(hsh[b][j], w2[d * 16 + j], s);
    gamma[t] = 1.f / (1.f + expf(-s));
}

// K3: per (b, 32x8 tile): stencil on y -> kappa -> logits -> a; out = x*(1+a)
__global__ __launch_bounds__(256) void k_fuse(const float* __restrict__ x,
                                              const float* __restrict__ y,
                                              const float* __restrict__ gamma,
                                              const float* __restrict__ fw,
                                              float* __restrict__ out) {
    __shared__ float tile[TH + 2][TW + 2];           // 10 x 34
    __shared__ float coef[NCR];
    __shared__ float sm[TH][TW];                     // 1+a per pixel

    const int b = blockIdx.z;
    const int w0 = blockIdx.x * TW, h0 = blockIdx.y * TH;
    const int t = threadIdx.x;
    const int tx = t % TW, ty = t / TW;

    if (t < NCR) coef[t] = fw[t] + gamma[b * NCR + t] * fw[NCR + t];
    __syncthreads();

    const float* yb = y + (size_t)b * NCR * NHW;
    float logit = 0.f;

    for (int c = 0; c < NCR; ++c) {
        const float* yc = yb + (size_t)c * NHW;
        for (int i = t; i < (TH + 2) * (TW + 2); i += 256) {
            const int iy = i / (TW + 2), ix = i % (TW + 2);
            const int gh = h0 + iy - 1, gw = w0 + ix - 1;
            float v = 0.f;
            if (gh >= 0 && gh < NH && gw >= 0 && gw < NW) v = yc[gh * NW + gw];
            tile[iy][ix] = v;
        }
        __syncthreads();

        const float a00 = tile[ty][tx],     a01 = tile[ty][tx + 1],     a02 = tile[ty][tx + 2];
        const float a10 = tile[ty + 1][tx], a11 = tile[ty + 1][tx + 1], a12 = tile[ty + 1][tx + 2];
        const float a20 = tile[ty + 2][tx], a21 = tile[ty + 2][tx + 1], a22 = tile[ty + 2][tx + 2];

        const float mu = (a00 + a01 + a02 + a10 + a11 + a12 + a20 + a21 + a22) * (1.f / 9.f);
        const float gx = (a00 - a02 + 2.f * (a10 - a12) + a20 - a22) * 0.125f;
        const float gy = (a00 + 2.f * a01 + a02 - a20 - 2.f * a21 - a22) * 0.125f;
        const float kappa = 1.f - fabsf(a11 - mu) / (fabsf(gx) + fabsf(gy) + KEPS);
        logit = fmaf(kappa, coef[c], logit);
        __syncthreads();
    }

    const float a = 1.f / (1.f + expf(-logit));
    sm[ty][tx] = 1.f + a;
    __syncthreads();

    // streaming multiply: remap threads to 4-wide float4 spans, 4 channel-groups
    const int cg = t >> 6;                           // 0..3
    const int rr = (t >> 3) & 7;                     // row 0..7
    const int cw = (t & 7) * 4;                      // col 0,4,...,28
    const float4 m4 = *reinterpret_cast<const float4*>(&sm[rr][cw]);

    const size_t base = (size_t)b * NC * NHW + (size_t)cg * NHW + (h0 + rr) * NW + (w0 + cw);
    const float* xp = x + base;
    float* op = out + base;
    const size_t stride = (size_t)4 * NHW;

#pragma unroll 4
    for (int it = 0; it < NC / 4; ++it) {
        float4 v = *reinterpret_cast<const float4*>(xp);
        float4 r;
        r.x = v.x * m4.x; r.y = v.y * m4.y; r.z = v.z * m4.z; r.w = v.w * m4.w;
        *reinterpret_cast<float4*>(op) = r;
        xp += stride; op += stride;
    }
}

extern "C" void kernel_launch(void* const* d_in, const int* in_sizes, int n_in,
                              void* d_out, int out_size, void* d_ws, size_t ws_size,
                              hipStream_t stream) {
    const float* x  = (const float*)d_in[0];
    const float* rw = (const float*)d_in[1];
    const float* w1 = (const float*)d_in[2];
    const float* b1 = (const float*)d_in[3];
    const float* w2 = (const float*)d_in[4];
    const float* b2 = (const float*)d_in[5];
    const float* fw = (const float*)d_in[6];
    float* out = (float*)d_out;

    float* y      = (float*)d_ws;                       // 13,107,200 floats
    float* pooled = y + (size_t)NB * NCR * NHW;         // 512 floats (sums)
    float* gamma  = pooled + NB * NCR;                  // 512 floats
    float* rwT    = gamma + NB * NCR;                   // 16384 floats

    k_tr<<<dim3(64), 256, 0, stream>>>(rw, rwT, pooled);
    k_reduce<<<dim3(NB * (NHW / 256)), 256, 0, stream>>>(x, rwT, y, pooled);
    k_gate<<<dim3(1), 512, 0, stream>>>(pooled, w1, b1, w2, b2, gamma);
    k_fuse<<<dim3(NW / TW, NH / TH, NB), 256, 0, stream>>>(x, y, gamma, fw, out);
}

// Round 4
// 366.652 us; speedup vs baseline: 1.3838x; 1.3398x over previous
//
#include <hip/hip_runtime.h>
#include <math.h>

constexpr int NB = 8;
constexpr int NC = 256;
constexpr int NCR = 64;
constexpr int NH = 160;
constexpr int NW = 160;
constexpr int NHW = NH * NW;           // 25600
constexpr float KEPS = 1e-4f;

constexpr int TW = 32;                 // tile width (k_fuse)
constexpr int TH = 8;                  // tile height (k_fuse)

// K0: transpose rw[d][c] -> rwT[c][d]; block 0 also zeroes pooledsum
__global__ __launch_bounds__(256) void k_tr(const float* __restrict__ rw,
                                            float* __restrict__ rwT,
                                            float* __restrict__ pooledsum) {
    const int i = blockIdx.x * 256 + threadIdx.x;    // over 16384
    const int d = i >> 8, c = i & 255;
    rwT[c * NCR + d] = rw[i];
    if (blockIdx.x == 0) {
        pooledsum[threadIdx.x] = 0.f;
        pooledsum[256 + threadIdx.x] = 0.f;
    }
}

#define FMA4(A, X, W) \
    A.x = fmaf((X).x, (W), A.x); A.y = fmaf((X).y, (W), A.y); \
    A.z = fmaf((X).z, (W), A.z); A.w = fmaf((X).w, (W), A.w)

#define YSTORE(J, A) \
    *reinterpret_cast<float4*>(yb + (size_t)(J) * NHW) = A

#define POOLRED(J, A) { \
    float s_ = (A).x + (A).y + (A).z + (A).w; \
    _Pragma("unroll") \
    for (int o_ = 32; o_ > 0; o_ >>= 1) s_ += __shfl_down(s_, o_, 64); \
    if (lane == 0) atomicAdd(&ps[(J)], s_); }

// K1: y[b,d,p] = sum_c x[b,c,p] * rwT[c][d]; also accumulates pooled sums.
// Thread = 4 pixels (float4 x) x 16 d. Acc = 16 named float4 (cannot spill to
// scratch via runtime indexing). Weights via LDS broadcast ds_read_b128.
__global__ __launch_bounds__(256, 1) void k_reduce(const float* __restrict__ x,
                                                   const float* __restrict__ rwT,
                                                   float* __restrict__ y,
                                                   float* __restrict__ pooledsum) {
    __shared__ float wlds[64 * NCR];                 // 16 KB, one 64-channel slice
    const int t = threadIdx.x;
    const int pg = t & 63;                           // pixel group (lane)
    const int dg = t >> 6;                           // wave id = d-group 0..3
    const int blocksPerImg = NHW / 256;              // 100
    const int b = blockIdx.x / blocksPerImg;
    const int p0 = (blockIdx.x % blocksPerImg) * 256 + pg * 4;

    const float* xb = x + (size_t)b * NC * NHW + p0;

    float4 A0{0,0,0,0},  A1{0,0,0,0},  A2{0,0,0,0},  A3{0,0,0,0};
    float4 A4{0,0,0,0},  A5{0,0,0,0},  A6{0,0,0,0},  A7{0,0,0,0};
    float4 A8{0,0,0,0},  A9{0,0,0,0},  A10{0,0,0,0}, A11{0,0,0,0};
    float4 A12{0,0,0,0}, A13{0,0,0,0}, A14{0,0,0,0}, A15{0,0,0,0};

    for (int cs = 0; cs < NC; cs += 64) {
        __syncthreads();                             // previous slice consumed
        {
            const float4* src = reinterpret_cast<const float4*>(rwT + (size_t)cs * NCR);
            float4* dst = reinterpret_cast<float4*>(wlds);
#pragma unroll
            for (int i = 0; i < 4; ++i) dst[i * 256 + t] = src[i * 256 + t];
        }
        __syncthreads();

#pragma unroll 4
        for (int cc = 0; cc < 64; ++cc) {
            const float4 x4 = *reinterpret_cast<const float4*>(xb + (size_t)(cs + cc) * NHW);
            const float4* wr = reinterpret_cast<const float4*>(wlds + cc * NCR + dg * 16);
            const float4 w0 = wr[0], w1 = wr[1], w2 = wr[2], w3 = wr[3];
            FMA4(A0,  x4, w0.x); FMA4(A1,  x4, w0.y); FMA4(A2,  x4, w0.z); FMA4(A3,  x4, w0.w);
            FMA4(A4,  x4, w1.x); FMA4(A5,  x4, w1.y); FMA4(A6,  x4, w1.z); FMA4(A7,  x4, w1.w);
            FMA4(A8,  x4, w2.x); FMA4(A9,  x4, w2.y); FMA4(A10, x4, w2.z); FMA4(A11, x4, w2.w);
            FMA4(A12, x4, w3.x); FMA4(A13, x4, w3.y); FMA4(A14, x4, w3.z); FMA4(A15, x4, w3.w);
        }
    }

    float* yb = y + (size_t)b * NCR * NHW + (size_t)(dg * 16) * NHW + p0;
    YSTORE(0, A0);   YSTORE(1, A1);   YSTORE(2, A2);   YSTORE(3, A3);
    YSTORE(4, A4);   YSTORE(5, A5);   YSTORE(6, A6);   YSTORE(7, A7);
    YSTORE(8, A8);   YSTORE(9, A9);   YSTORE(10, A10); YSTORE(11, A11);
    YSTORE(12, A12); YSTORE(13, A13); YSTORE(14, A14); YSTORE(15, A15);

    const int lane = t & 63;
    float* ps = pooledsum + b * NCR + dg * 16;
    POOLRED(0, A0);   POOLRED(1, A1);   POOLRED(2, A2);   POOLRED(3, A3);
    POOLRED(4, A4);   POOLRED(5, A5);   POOLRED(6, A6);   POOLRED(7, A7);
    POOLRED(8, A8);   POOLRED(9, A9);   POOLRED(10, A10); POOLRED(11, A11);
    POOLRED(12, A12); POOLRED(13, A13); POOLRED(14, A14); POOLRED(15, A15);
}

// K2: gamma[b,d] = sigmoid(relu(mean@w1^T+b1)@w2^T+b2); pooledsum -> mean
__global__ __launch_bounds__(512) void k_gate(const float* __restrict__ pooledsum,
                                              const float* __restrict__ w1,
                                              const float* __restrict__ b1,
                                              const float* __restrict__ w2,
                                              const float* __restrict__ b2,
                                              float* __restrict__ gamma) {
    __shared__ float hsh[NB][16];
    const int t = threadIdx.x;
    constexpr float inv = 1.f / (float)NHW;
    if (t < NB * 16) {
        const int b = t / 16, j = t % 16;
        float s = b1[j];
        for (int d = 0; d < NCR; ++d)
            s = fmaf(pooledsum[b * NCR + d] * inv, w1[j * NCR + d], s);
        hsh[b][j] = fmaxf(s, 0.f);
    }
    __syncthreads();
    const int b = t / NCR, d = t % NCR;
    float s = b2[d];
#pragma unroll
    for (int j = 0; j < 16; ++j) s = fmaf(hsh[b][j], w2[d * 16 + j], s);
    gamma[t] = 1.f / (1.f + expf(-s));
}

// K3: per (b, 32x8 tile): stencil on y -> kappa -> logits -> a; out = x*(1+a)
__global__ __launch_bounds__(256) void k_fuse(const float* __restrict__ x,
                                              const float* __restrict__ y,
                                              const float* __restrict__ gamma,
                                              const float* __restrict__ fw,
                                              float* __restrict__ out) {
    __shared__ float tile[TH + 2][TW + 2];           // 10 x 34
    __shared__ float coef[NCR];
    __shared__ float sm[TH][TW];                     // 1+a per pixel

    const int b = blockIdx.z;
    const int w0 = blockIdx.x * TW, h0 = blockIdx.y * TH;
    const int t = threadIdx.x;
    const int tx = t % TW, ty = t / TW;

    if (t < NCR) coef[t] = fw[t] + gamma[b * NCR + t] * fw[NCR + t];
    __syncthreads();

    const float* yb = y + (size_t)b * NCR * NHW;
    float logit = 0.f;

    for (int c = 0; c < NCR; ++c) {
        const float* yc = yb + (size_t)c * NHW;
        for (int i = t; i < (TH + 2) * (TW + 2); i += 256) {
            const int iy = i / (TW + 2), ix = i % (TW + 2);
            const int gh = h0 + iy - 1, gw = w0 + ix - 1;
            float v = 0.f;
            if (gh >= 0 && gh < NH && gw >= 0 && gw < NW) v = yc[gh * NW + gw];
            tile[iy][ix] = v;
        }
        __syncthreads();

        const float a00 = tile[ty][tx],     a01 = tile[ty][tx + 1],     a02 = tile[ty][tx + 2];
        const float a10 = tile[ty + 1][tx], a11 = tile[ty + 1][tx + 1], a12 = tile[ty + 1][tx + 2];
        const float a20 = tile[ty + 2][tx], a21 = tile[ty + 2][tx + 1], a22 = tile[ty + 2][tx + 2];

        const float mu = (a00 + a01 + a02 + a10 + a11 + a12 + a20 + a21 + a22) * (1.f / 9.f);
        const float gx = (a00 - a02 + 2.f * (a10 - a12) + a20 - a22) * 0.125f;
        const float gy = (a00 + 2.f * a01 + a02 - a20 - 2.f * a21 - a22) * 0.125f;
        const float kappa = 1.f - fabsf(a11 - mu) / (fabsf(gx) + fabsf(gy) + KEPS);
        logit = fmaf(kappa, coef[c], logit);
        __syncthreads();
    }

    const float a = 1.f / (1.f + expf(-logit));
    sm[ty][tx] = 1.f + a;
    __syncthreads();

    // streaming multiply: remap threads to 4-wide float4 spans, 4 channel-groups
    const int cg = t >> 6;                           // 0..3
    const int rr = (t >> 3) & 7;                     // row 0..7
    const int cw = (t & 7) * 4;                      // col 0,4,...,28
    const float4 m4 = *reinterpret_cast<const float4*>(&sm[rr][cw]);

    const size_t base = (size_t)b * NC * NHW + (size_t)cg * NHW + (h0 + rr) * NW + (w0 + cw);
    const float* xp = x + base;
    float* op = out + base;
    const size_t stride = (size_t)4 * NHW;

#pragma unroll 4
    for (int it = 0; it < NC / 4; ++it) {
        float4 v = *reinterpret_cast<const float4*>(xp);
        float4 r;
        r.x = v.x * m4.x; r.y = v.y * m4.y; r.z = v.z * m4.z; r.w = v.w * m4.w;
        *reinterpret_cast<float4*>(op) = r;
        xp += stride; op += stride;
    }
}

extern "C" void kernel_launch(void* const* d_in, const int* in_sizes, int n_in,
                              void* d_out, int out_size, void* d_ws, size_t ws_size,
                              hipStream_t stream) {
    const float* x  = (const float*)d_in[0];
    const float* rw = (const float*)d_in[1];
    const float* w1 = (const float*)d_in[2];
    const float* b1 = (const float*)d_in[3];
    const float* w2 = (const float*)d_in[4];
    const float* b2 = (const float*)d_in[5];
    const float* fw = (const float*)d_in[6];
    float* out = (float*)d_out;

    float* y      = (float*)d_ws;                       // 13,107,200 floats
    float* pooled = y + (size_t)NB * NCR * NHW;         // 512 floats (sums)
    float* gamma  = pooled + NB * NCR;                  // 512 floats
    float* rwT    = gamma + NB * NCR;                   // 16384 floats

    k_tr<<<dim3(64), 256, 0, stream>>>(rw, rwT, pooled);
    k_reduce<<<dim3(NB * (NHW / 256)), 256, 0, stream>>>(x, rwT, y, pooled);
    k_gate<<<dim3(1), 512, 0, stream>>>(pooled, w1, b1, w2, b2, gamma);
    k_fuse<<<dim3(NW / TW, NH / TH, NB), 256, 0, stream>>>(x, y, gamma, fw, out);
}

// Round 5
// 307.489 us; speedup vs baseline: 1.6501x; 1.1924x over previous
//
#include <hip/hip_runtime.h>
#include <math.h>

constexpr int NB = 8;
constexpr int NC = 256;
constexpr int NCR = 64;
constexpr int NH = 160;
constexpr int NW = 160;
constexpr int NHW = NH * NW;           // 25600
constexpr float KEPS = 1e-4f;

constexpr int TW = 32;                 // tile width (k_fuse)
constexpr int TH = 8;                  // tile height (k_fuse)

// K0: transpose rw[d][c] -> rwT[c][d]; block 0 also zeroes pooledsum
__global__ __launch_bounds__(256) void k_tr(const float* __restrict__ rw,
                                            float* __restrict__ rwT,
                                            float* __restrict__ pooledsum) {
    const int i = blockIdx.x * 256 + threadIdx.x;    // over 16384
    const int d = i >> 8, c = i & 255;
    rwT[c * NCR + d] = rw[i];
    if (blockIdx.x == 0) {
        pooledsum[threadIdx.x] = 0.f;
        pooledsum[256 + threadIdx.x] = 0.f;
    }
}

#define FMA4(A, X, W) \
    A.x = fmaf((X).x, (W), A.x); A.y = fmaf((X).y, (W), A.y); \
    A.z = fmaf((X).z, (W), A.z); A.w = fmaf((X).w, (W), A.w)

#define YSTORE(J, A) \
    *reinterpret_cast<float4*>(yb + (size_t)(J) * NHW) = A

#define POOLRED(J, A) { \
    float s_ = (A).x + (A).y + (A).z + (A).w; \
    _Pragma("unroll") \
    for (int o_ = 32; o_ > 0; o_ >>= 1) s_ += __shfl_down(s_, o_, 64); \
    if (lane == 0) atomicAdd(&ps[(J)], s_); }

// K1: y[b,d,p] = sum_c x[b,c,p] * rwT[c][d]; also accumulates pooled sums.
// Thread = 4 pixels (float4 x) x 16 d. Acc = 16 named float4.
// ALL weights staged in LDS once (64 KB) -> barrier-free 256-channel main loop.
// unroll 8 -> 8 global loads in flight: 1024 cy FMA per burst > ~900 cy HBM lat.
__global__ __launch_bounds__(256, 1) void k_reduce(const float* __restrict__ x,
                                                   const float* __restrict__ rwT,
                                                   float* __restrict__ y,
                                                   float* __restrict__ pooledsum) {
    __shared__ float wlds[NC * NCR];                 // 65536 B (static LDS cap)
    const int t = threadIdx.x;
    const int pg = t & 63;                           // lane
    const int dg = t >> 6;                           // wave id = d-group 0..3
    const int blocksPerImg = NHW / 256;              // 100
    const int b = blockIdx.x / blocksPerImg;
    const int p0 = (blockIdx.x % blocksPerImg) * 256 + pg * 4;

    // stage all 16384 weights: 4096 float4, 16 per thread
    {
        const float4* src = reinterpret_cast<const float4*>(rwT);
        float4* dst = reinterpret_cast<float4*>(wlds);
#pragma unroll
        for (int i = 0; i < 16; ++i) dst[i * 256 + t] = src[i * 256 + t];
    }
    __syncthreads();

    const float* xb = x + (size_t)b * NC * NHW + p0;

    float4 A0{0,0,0,0},  A1{0,0,0,0},  A2{0,0,0,0},  A3{0,0,0,0};
    float4 A4{0,0,0,0},  A5{0,0,0,0},  A6{0,0,0,0},  A7{0,0,0,0};
    float4 A8{0,0,0,0},  A9{0,0,0,0},  A10{0,0,0,0}, A11{0,0,0,0};
    float4 A12{0,0,0,0}, A13{0,0,0,0}, A14{0,0,0,0}, A15{0,0,0,0};

#pragma unroll 8
    for (int c = 0; c < NC; ++c) {
        const float4 x4 = *reinterpret_cast<const float4*>(xb + (size_t)c * NHW);
        const float4* wr = reinterpret_cast<const float4*>(wlds + c * NCR + dg * 16);
        const float4 w0 = wr[0], w1 = wr[1], w2 = wr[2], w3 = wr[3];
        FMA4(A0,  x4, w0.x); FMA4(A1,  x4, w0.y); FMA4(A2,  x4, w0.z); FMA4(A3,  x4, w0.w);
        FMA4(A4,  x4, w1.x); FMA4(A5,  x4, w1.y); FMA4(A6,  x4, w1.z); FMA4(A7,  x4, w1.w);
        FMA4(A8,  x4, w2.x); FMA4(A9,  x4, w2.y); FMA4(A10, x4, w2.z); FMA4(A11, x4, w2.w);
        FMA4(A12, x4, w3.x); FMA4(A13, x4, w3.y); FMA4(A14, x4, w3.z); FMA4(A15, x4, w3.w);
    }

    float* yb = y + (size_t)b * NCR * NHW + (size_t)(dg * 16) * NHW + p0;
    YSTORE(0, A0);   YSTORE(1, A1);   YSTORE(2, A2);   YSTORE(3, A3);
    YSTORE(4, A4);   YSTORE(5, A5);   YSTORE(6, A6);   YSTORE(7, A7);
    YSTORE(8, A8);   YSTORE(9, A9);   YSTORE(10, A10); YSTORE(11, A11);
    YSTORE(12, A12); YSTORE(13, A13); YSTORE(14, A14); YSTORE(15, A15);

    const int lane = t & 63;
    float* ps = pooledsum + b * NCR + dg * 16;
    POOLRED(0, A0);   POOLRED(1, A1);   POOLRED(2, A2);   POOLRED(3, A3);
    POOLRED(4, A4);   POOLRED(5, A5);   POOLRED(6, A6);   POOLRED(7, A7);
    POOLRED(8, A8);   POOLRED(9, A9);   POOLRED(10, A10); POOLRED(11, A11);
    POOLRED(12, A12); POOLRED(13, A13); POOLRED(14, A14); POOLRED(15, A15);
}

// K2: gamma[b,d] = sigmoid(relu(mean@w1^T+b1)@w2^T+b2); pooledsum -> mean
__global__ __launch_bounds__(512) void k_gate(const float* __restrict__ pooledsum,
                                              const float* __restrict__ w1,
                                              const float* __restrict__ b1,
                                              const float* __restrict__ w2,
                                              const float* __restrict__ b2,
                                              float* __restrict__ gamma) {
    __shared__ float hsh[NB][16];
    const int t = threadIdx.x;
    constexpr float inv = 1.f / (float)NHW;
    if (t < NB * 16) {
        const int b = t / 16, j = t % 16;
        float s = b1[j];
        for (int d = 0; d < NCR; ++d)
            s = fmaf(pooledsum[b * NCR + d] * inv, w1[j * NCR + d], s);
        hsh[b][j] = fmaxf(s, 0.f);
    }
    __syncthreads();
    const int b = t / NCR, d = t % NCR;
    float s = b2[d];
#pragma unroll
    for (int j = 0; j < 16; ++j) s = fmaf(hsh[b][j], w2[d * 16 + j], s);
    gamma[t] = 1.f / (1.f + expf(-s));
}

// K3: per (b, 32x8 tile): stencil on y -> kappa -> logits -> a; out = x*(1+a)
__global__ __launch_bounds__(256) void k_fuse(const float* __restrict__ x,
                                              const float* __restrict__ y,
                                              const float* __restrict__ gamma,
                                              const float* __restrict__ fw,
                                              float* __restrict__ out) {
    __shared__ float tile[TH + 2][TW + 2];           // 10 x 34
    __shared__ float coef[NCR];
    __shared__ float sm[TH][TW];                     // 1+a per pixel

    const int b = blockIdx.z;
    const int w0 = blockIdx.x * TW, h0 = blockIdx.y * TH;
    const int t = threadIdx.x;
    const int tx = t % TW, ty = t / TW;

    if (t < NCR) coef[t] = fw[t] + gamma[b * NCR + t] * fw[NCR + t];
    __syncthreads();

    const float* yb = y + (size_t)b * NCR * NHW;
    float logit = 0.f;

    for (int c = 0; c < NCR; ++c) {
        const float* yc = yb + (size_t)c * NHW;
        for (int i = t; i < (TH + 2) * (TW + 2); i += 256) {
            const int iy = i / (TW + 2), ix = i % (TW + 2);
            const int gh = h0 + iy - 1, gw = w0 + ix - 1;
            float v = 0.f;
            if (gh >= 0 && gh < NH && gw >= 0 && gw < NW) v = yc[gh * NW + gw];
            tile[iy][ix] = v;
        }
        __syncthreads();

        const float a00 = tile[ty][tx],     a01 = tile[ty][tx + 1],     a02 = tile[ty][tx + 2];
        const float a10 = tile[ty + 1][tx], a11 = tile[ty + 1][tx + 1], a12 = tile[ty + 1][tx + 2];
        const float a20 = tile[ty + 2][tx], a21 = tile[ty + 2][tx + 1], a22 = tile[ty + 2][tx + 2];

        const float mu = (a00 + a01 + a02 + a10 + a11 + a12 + a20 + a21 + a22) * (1.f / 9.f);
        const float gx = (a00 - a02 + 2.f * (a10 - a12) + a20 - a22) * 0.125f;
        const float gy = (a00 + 2.f * a01 + a02 - a20 - 2.f * a21 - a22) * 0.125f;
        const float kappa = 1.f - fabsf(a11 - mu) / (fabsf(gx) + fabsf(gy) + KEPS);
        logit = fmaf(kappa, coef[c], logit);
        __syncthreads();
    }

    const float a = 1.f / (1.f + expf(-logit));
    sm[ty][tx] = 1.f + a;
    __syncthreads();

    // streaming multiply: remap threads to 4-wide float4 spans, 4 channel-groups
    const int cg = t >> 6;                           // 0..3
    const int rr = (t >> 3) & 7;                     // row 0..7
    const int cw = (t & 7) * 4;                      // col 0,4,...,28
    const float4 m4 = *reinterpret_cast<const float4*>(&sm[rr][cw]);

    const size_t base = (size_t)b * NC * NHW + (size_t)cg * NHW + (h0 + rr) * NW + (w0 + cw);
    const float* xp = x + base;
    float* op = out + base;
    const size_t stride = (size_t)4 * NHW;

#pragma unroll 4
    for (int it = 0; it < NC / 4; ++it) {
        float4 v = *reinterpret_cast<const float4*>(xp);
        float4 r;
        r.x = v.x * m4.x; r.y = v.y * m4.y; r.z = v.z * m4.z; r.w = v.w * m4.w;
        *reinterpret_cast<float4*>(op) = r;
        xp += stride; op += stride;
    }
}

extern "C" void kernel_launch(void* const* d_in, const int* in_sizes, int n_in,
                              void* d_out, int out_size, void* d_ws, size_t ws_size,
                              hipStream_t stream) {
    const float* x  = (const float*)d_in[0];
    const float* rw = (const float*)d_in[1];
    const float* w1 = (const float*)d_in[2];
    const float* b1 = (const float*)d_in[3];
    const float* w2 = (const float*)d_in[4];
    const float* b2 = (const float*)d_in[5];
    const float* fw = (const float*)d_in[6];
    float* out = (float*)d_out;

    float* y      = (float*)d_ws;                       // 13,107,200 floats
    float* pooled = y + (size_t)NB * NCR * NHW;         // 512 floats (sums)
    float* gamma  = pooled + NB * NCR;                  // 512 floats
    float* rwT    = gamma + NB * NCR;                   // 16384 floats

    k_tr<<<dim3(64), 256, 0, stream>>>(rw, rwT, pooled);
    k_reduce<<<dim3(NB * (NHW / 256)), 256, 0, stream>>>(x, rwT, y, pooled);
    k_gate<<<dim3(1), 512, 0, stream>>>(pooled, w1, b1, w2, b2, gamma);
    k_fuse<<<dim3(NW / TW, NH / TH, NB), 256, 0, stream>>>(x, y, gamma, fw, out);
}

// Round 6
// 304.891 us; speedup vs baseline: 1.6641x; 1.0085x over previous
//
#include <hip/hip_runtime.h>
#include <math.h>

constexpr int NB = 8;
constexpr int NC = 256;
constexpr int NCR = 64;
constexpr int NH = 160;
constexpr int NW = 160;
constexpr int NHW = NH * NW;           // 25600
constexpr float KEPS = 1e-4f;

constexpr int TW = 32;                 // tile width (k_logits)
constexpr int TH = 8;                  // tile height (k_logits)

// K0: transpose rw[d][c] -> rwT[c][d]; block 0 also zeroes pooledsum
__global__ __launch_bounds__(256) void k_tr(const float* __restrict__ rw,
                                            float* __restrict__ rwT,
                                            float* __restrict__ pooledsum) {
    const int i = blockIdx.x * 256 + threadIdx.x;    // over 16384
    const int d = i >> 8, c = i & 255;
    rwT[c * NCR + d] = rw[i];
    if (blockIdx.x == 0) {
        pooledsum[threadIdx.x] = 0.f;
        pooledsum[256 + threadIdx.x] = 0.f;
    }
}

#define FMA4(A, X, W) \
    A.x = fmaf((X).x, (W), A.x); A.y = fmaf((X).y, (W), A.y); \
    A.z = fmaf((X).z, (W), A.z); A.w = fmaf((X).w, (W), A.w)

#define YSTORE(J, A) \
    *reinterpret_cast<float4*>(yb + (size_t)(J) * NHW) = A

#define POOLRED(J, A) { \
    float s_ = (A).x + (A).y + (A).z + (A).w; \
    _Pragma("unroll") \
    for (int o_ = 32; o_ > 0; o_ >>= 1) s_ += __shfl_down(s_, o_, 64); \
    if (lane == 0) atomicAdd(&ps[(J)], s_); }

// K1: y[b,d,p] = sum_c x[b,c,p] * rwT[c][d]; also accumulates pooled sums.
// Thread = 4 pixels (float4 x) x 16 d. Acc = 16 named float4.
// All weights in LDS (64 KB, barrier-free main loop). Software-pipelined:
// next 8 x-loads issued BEFORE current 8 channels' FMAs -> 1024cy FMA hides
// ~900cy HBM latency.
__global__ __launch_bounds__(256, 1) void k_reduce(const float* __restrict__ x,
                                                   const float* __restrict__ rwT,
                                                   float* __restrict__ y,
                                                   float* __restrict__ pooledsum) {
    __shared__ float wlds[NC * NCR];                 // 65536 B
    const int t = threadIdx.x;
    const int pg = t & 63;                           // lane
    const int dg = t >> 6;                           // wave id = d-group 0..3
    const int blocksPerImg = NHW / 256;              // 100
    const int b = blockIdx.x / blocksPerImg;
    const int p0 = (blockIdx.x % blocksPerImg) * 256 + pg * 4;

    {   // stage all 16384 weights: 4096 float4, 16 per thread
        const float4* src = reinterpret_cast<const float4*>(rwT);
        float4* dst = reinterpret_cast<float4*>(wlds);
#pragma unroll
        for (int i = 0; i < 16; ++i) dst[i * 256 + t] = src[i * 256 + t];
    }
    __syncthreads();

    const float* xb = x + (size_t)b * NC * NHW + p0;

    float4 A0{0,0,0,0},  A1{0,0,0,0},  A2{0,0,0,0},  A3{0,0,0,0};
    float4 A4{0,0,0,0},  A5{0,0,0,0},  A6{0,0,0,0},  A7{0,0,0,0};
    float4 A8{0,0,0,0},  A9{0,0,0,0},  A10{0,0,0,0}, A11{0,0,0,0};
    float4 A12{0,0,0,0}, A13{0,0,0,0}, A14{0,0,0,0}, A15{0,0,0,0};

    float4 xc[8], xn[8];                             // static-indexed only
#pragma unroll
    for (int i = 0; i < 8; ++i)
        xc[i] = *reinterpret_cast<const float4*>(xb + (size_t)i * NHW);

    for (int cs = 0; cs < NC; cs += 8) {
        if (cs + 8 < NC) {
#pragma unroll
            for (int i = 0; i < 8; ++i)
                xn[i] = *reinterpret_cast<const float4*>(xb + (size_t)(cs + 8 + i) * NHW);
        }
#pragma unroll
        for (int i = 0; i < 8; ++i) {
            const float4 x4 = xc[i];
            const float4* wr = reinterpret_cast<const float4*>(wlds + (cs + i) * NCR + dg * 16);
            const float4 w0 = wr[0], w1 = wr[1], w2 = wr[2], w3 = wr[3];
            FMA4(A0,  x4, w0.x); FMA4(A1,  x4, w0.y); FMA4(A2,  x4, w0.z); FMA4(A3,  x4, w0.w);
            FMA4(A4,  x4, w1.x); FMA4(A5,  x4, w1.y); FMA4(A6,  x4, w1.z); FMA4(A7,  x4, w1.w);
            FMA4(A8,  x4, w2.x); FMA4(A9,  x4, w2.y); FMA4(A10, x4, w2.z); FMA4(A11, x4, w2.w);
            FMA4(A12, x4, w3.x); FMA4(A13, x4, w3.y); FMA4(A14, x4, w3.z); FMA4(A15, x4, w3.w);
        }
        if (cs + 8 < NC) {
#pragma unroll
            for (int i = 0; i < 8; ++i) xc[i] = xn[i];
        }
    }

    float* yb = y + (size_t)b * NCR * NHW + (size_t)(dg * 16) * NHW + p0;
    YSTORE(0, A0);   YSTORE(1, A1);   YSTORE(2, A2);   YSTORE(3, A3);
    YSTORE(4, A4);   YSTORE(5, A5);   YSTORE(6, A6);   YSTORE(7, A7);
    YSTORE(8, A8);   YSTORE(9, A9);   YSTORE(10, A10); YSTORE(11, A11);
    YSTORE(12, A12); YSTORE(13, A13); YSTORE(14, A14); YSTORE(15, A15);

    const int lane = t & 63;
    float* ps = pooledsum + b * NCR + dg * 16;
    POOLRED(0, A0);   POOLRED(1, A1);   POOLRED(2, A2);   POOLRED(3, A3);
    POOLRED(4, A4);   POOLRED(5, A5);   POOLRED(6, A6);   POOLRED(7, A7);
    POOLRED(8, A8);   POOLRED(9, A9);   POOLRED(10, A10); POOLRED(11, A11);
    POOLRED(12, A12); POOLRED(13, A13); POOLRED(14, A14); POOLRED(15, A15);
}

// K2: gamma[b,d] = sigmoid(relu(mean@w1^T+b1)@w2^T+b2); pooledsum -> mean
__global__ __launch_bounds__(512) void k_gate(const float* __restrict__ pooledsum,
                                              const float* __restrict__ w1,
                                              const float* __restrict__ b1,
                                              const float* __restrict__ w2,
                                              const float* __restrict__ b2,
                                              float* __restrict__ gamma) {
    __shared__ float hsh[NB][16];
    const int t = threadIdx.x;
    constexpr float inv = 1.f / (float)NHW;
    if (t < NB * 16) {
        const int b = t / 16, j = t % 16;
        float s = b1[j];
        for (int d = 0; d < NCR; ++d)
            s = fmaf(pooledsum[b * NCR + d] * inv, w1[j * NCR + d], s);
        hsh[b][j] = fmaxf(s, 0.f);
    }
    __syncthreads();
    const int b = t / NCR, d = t % NCR;
    float s = b2[d];
#pragma unroll
    for (int j = 0; j < 16; ++j) s = fmaf(hsh[b][j], w2[d * 16 + j], s);
    gamma[t] = 1.f / (1.f + expf(-s));
}

// K3a: per (b, 32x8 tile): stencil on y -> kappa -> logits -> m = 1+sigmoid
__global__ __launch_bounds__(256) void k_logits(const float* __restrict__ y,
                                                const float* __restrict__ gamma,
                                                const float* __restrict__ fw,
                                                float* __restrict__ m) {
    __shared__ float tile[TH + 2][TW + 2];           // 10 x 34
    __shared__ float coef[NCR];

    const int b = blockIdx.z;
    const int w0 = blockIdx.x * TW, h0 = blockIdx.y * TH;
    const int t = threadIdx.x;
    const int tx = t % TW, ty = t / TW;

    if (t < NCR) coef[t] = fw[t] + gamma[b * NCR + t] * fw[NCR + t];
    __syncthreads();

    const float* yb = y + (size_t)b * NCR * NHW;
    float logit = 0.f;

    for (int c = 0; c < NCR; ++c) {
        const float* yc = yb + (size_t)c * NHW;
        for (int i = t; i < (TH + 2) * (TW + 2); i += 256) {
            const int iy = i / (TW + 2), ix = i % (TW + 2);
            const int gh = h0 + iy - 1, gw = w0 + ix - 1;
            float v = 0.f;
            if (gh >= 0 && gh < NH && gw >= 0 && gw < NW) v = yc[gh * NW + gw];
            tile[iy][ix] = v;
        }
        __syncthreads();

        const float a00 = tile[ty][tx],     a01 = tile[ty][tx + 1],     a02 = tile[ty][tx + 2];
        const float a10 = tile[ty + 1][tx], a11 = tile[ty + 1][tx + 1], a12 = tile[ty + 1][tx + 2];
        const float a20 = tile[ty + 2][tx], a21 = tile[ty + 2][tx + 1], a22 = tile[ty + 2][tx + 2];

        const float mu = (a00 + a01 + a02 + a10 + a11 + a12 + a20 + a21 + a22) * (1.f / 9.f);
        const float gx = (a00 - a02 + 2.f * (a10 - a12) + a20 - a22) * 0.125f;
        const float gy = (a00 + 2.f * a01 + a02 - a20 - 2.f * a21 - a22) * 0.125f;
        const float kappa = 1.f - fabsf(a11 - mu) / (fabsf(gx) + fabsf(gy) + KEPS);
        logit = fmaf(kappa, coef[c], logit);
        __syncthreads();
    }

    const float a = 1.f / (1.f + expf(-logit));
    m[(size_t)b * NHW + (h0 + ty) * NW + (w0 + tx)] = 1.f + a;
}

// K3b: pure stream out = x * m. Block: 256 thr over 1024 px; 4 channels each.
// Grid (25, 64, 8). Zero integer division; m row stays L2-hot.
__global__ __launch_bounds__(256) void k_mul(const float* __restrict__ x,
                                             const float* __restrict__ m,
                                             float* __restrict__ out) {
    const int b = blockIdx.z;
    const int c0 = blockIdx.y * 4;
    const int p = blockIdx.x * 1024 + threadIdx.x * 4;

    const float4 mv = *reinterpret_cast<const float4*>(m + (size_t)b * NHW + p);
    const size_t base = (size_t)b * NC * NHW + (size_t)c0 * NHW + p;
    const float* xp = x + base;
    float* op = out + base;

#pragma unroll
    for (int cc = 0; cc < 4; ++cc) {
        const float4 v = *reinterpret_cast<const float4*>(xp + (size_t)cc * NHW);
        float4 r;
        r.x = v.x * mv.x; r.y = v.y * mv.y; r.z = v.z * mv.z; r.w = v.w * mv.w;
        *reinterpret_cast<float4*>(op + (size_t)cc * NHW) = r;
    }
}

extern "C" void kernel_launch(void* const* d_in, const int* in_sizes, int n_in,
                              void* d_out, int out_size, void* d_ws, size_t ws_size,
                              hipStream_t stream) {
    const float* x  = (const float*)d_in[0];
    const float* rw = (const float*)d_in[1];
    const float* w1 = (const float*)d_in[2];
    const float* b1 = (const float*)d_in[3];
    const float* w2 = (const float*)d_in[4];
    const float* b2 = (const float*)d_in[5];
    const float* fw = (const float*)d_in[6];
    float* out = (float*)d_out;

    float* y      = (float*)d_ws;                       // 13,107,200 floats
    float* pooled = y + (size_t)NB * NCR * NHW;         // 512 floats (sums)
    float* gamma  = pooled + NB * NCR;                  // 512 floats
    float* rwT    = gamma + NB * NCR;                   // 16384 floats
    float* m      = rwT + NC * NCR;                     // 204800 floats

    k_tr<<<dim3(64), 256, 0, stream>>>(rw, rwT, pooled);
    k_reduce<<<dim3(NB * (NHW / 256)), 256, 0, stream>>>(x, rwT, y, pooled);
    k_gate<<<dim3(1), 512, 0, stream>>>(pooled, w1, b1, w2, b2, gamma);
    k_logits<<<dim3(NW / TW, NH / TH, NB), 256, 0, stream>>>(y, gamma, fw, m);
    k_mul<<<dim3(NHW / 1024, NC / 4, NB), 256, 0, stream>>>(x, m, out);
}

// Round 7
// 265.741 us; speedup vs baseline: 1.9093x; 1.1473x over previous
//
#include <hip/hip_runtime.h>
#include <math.h>

constexpr int NB = 8;
constexpr int NC = 256;
constexpr int NCR = 64;
constexpr int NH = 160;
constexpr int NW = 160;
constexpr int NHW = NH * NW;           // 25600
constexpr float KEPS = 1e-4f;

constexpr int TW = 32;                 // tile width (k_logits)
constexpr int TH = 8;                  // tile height (k_logits)

// K0: transpose rw[d][c] -> rwT[c][d]; block 0 also zeroes pooledsum
__global__ __launch_bounds__(256) void k_tr(const float* __restrict__ rw,
                                            float* __restrict__ rwT,
                                            float* __restrict__ pooledsum) {
    const int i = blockIdx.x * 256 + threadIdx.x;    // over 16384
    const int d = i >> 8, c = i & 255;
    rwT[c * NCR + d] = rw[i];
    if (blockIdx.x == 0) {
        pooledsum[threadIdx.x] = 0.f;
        pooledsum[256 + threadIdx.x] = 0.f;
    }
}

#define FMA4(A, X, W) \
    A.x = fmaf((X).x, (W), A.x); A.y = fmaf((X).y, (W), A.y); \
    A.z = fmaf((X).z, (W), A.z); A.w = fmaf((X).w, (W), A.w)

// K1: y[b,d,p] = sum_c x[b,c,p] * rwT[c][d]; also accumulates pooled sums.
// 8 px/lane (2x float4) x 16 d/thread: per wave-channel 256cy FMA vs 4 LDS
// broadcast reads -> LDS pipe no longer the limiter (was 2.1:1 at 4 px/lane).
// Block covers 512 px -> 50 blocks/img, no tail. 4-channel-deep x prefetch.
__global__ __launch_bounds__(256, 1) void k_reduce(const float* __restrict__ x,
                                                   const float* __restrict__ rwT,
                                                   float* __restrict__ y,
                                                   float* __restrict__ pooledsum) {
    __shared__ float wlds[NC * NCR];                 // 65536 B
    const int t = threadIdx.x;
    const int lane = t & 63;
    const int dg = t >> 6;                           // wave id = d-group 0..3
    const int b = blockIdx.y;
    const int p0 = blockIdx.x * 512 + lane * 4;      // group0; group1 = +256

    {   // stage all 16384 weights: 4096 float4, 16 per thread
        const float4* src = reinterpret_cast<const float4*>(rwT);
        float4* dst = reinterpret_cast<float4*>(wlds);
#pragma unroll
        for (int i = 0; i < 16; ++i) dst[i * 256 + t] = src[i * 256 + t];
    }
    __syncthreads();

    const float* xb = x + (size_t)b * NC * NHW + p0;

    float4 Aa[16], Ab[16];
#pragma unroll
    for (int d = 0; d < 16; ++d) { Aa[d] = float4{0,0,0,0}; Ab[d] = float4{0,0,0,0}; }

    float4 xc0[4], xc1[4], xn0[4], xn1[4];
#pragma unroll
    for (int j = 0; j < 4; ++j) {
        xc0[j] = *reinterpret_cast<const float4*>(xb + (size_t)j * NHW);
        xc1[j] = *reinterpret_cast<const float4*>(xb + (size_t)j * NHW + 256);
    }

    for (int cs = 0; cs < NC; cs += 4) {
        if (cs + 4 < NC) {
#pragma unroll
            for (int j = 0; j < 4; ++j) {
                xn0[j] = *reinterpret_cast<const float4*>(xb + (size_t)(cs + 4 + j) * NHW);
                xn1[j] = *reinterpret_cast<const float4*>(xb + (size_t)(cs + 4 + j) * NHW + 256);
            }
        }
#pragma unroll
        for (int j = 0; j < 4; ++j) {
            const float4* wr = reinterpret_cast<const float4*>(wlds + (cs + j) * NCR + dg * 16);
            const float4 w0 = wr[0], w1 = wr[1], w2 = wr[2], w3 = wr[3];
            const float4 u = xc0[j], v = xc1[j];
            FMA4(Aa[0],  u, w0.x); FMA4(Ab[0],  v, w0.x);
            FMA4(Aa[1],  u, w0.y); FMA4(Ab[1],  v, w0.y);
            FMA4(Aa[2],  u, w0.z); FMA4(Ab[2],  v, w0.z);
            FMA4(Aa[3],  u, w0.w); FMA4(Ab[3],  v, w0.w);
            FMA4(Aa[4],  u, w1.x); FMA4(Ab[4],  v, w1.x);
            FMA4(Aa[5],  u, w1.y); FMA4(Ab[5],  v, w1.y);
            FMA4(Aa[6],  u, w1.z); FMA4(Ab[6],  v, w1.z);
            FMA4(Aa[7],  u, w1.w); FMA4(Ab[7],  v, w1.w);
            FMA4(Aa[8],  u, w2.x); FMA4(Ab[8],  v, w2.x);
            FMA4(Aa[9],  u, w2.y); FMA4(Ab[9],  v, w2.y);
            FMA4(Aa[10], u, w2.z); FMA4(Ab[10], v, w2.z);
            FMA4(Aa[11], u, w2.w); FMA4(Ab[11], v, w2.w);
            FMA4(Aa[12], u, w3.x); FMA4(Ab[12], v, w3.x);
            FMA4(Aa[13], u, w3.y); FMA4(Ab[13], v, w3.y);
            FMA4(Aa[14], u, w3.z); FMA4(Ab[14], v, w3.z);
            FMA4(Aa[15], u, w3.w); FMA4(Ab[15], v, w3.w);
        }
        if (cs + 4 < NC) {
#pragma unroll
            for (int j = 0; j < 4; ++j) { xc0[j] = xn0[j]; xc1[j] = xn1[j]; }
        }
    }

    float* yb = y + (size_t)b * NCR * NHW + (size_t)(dg * 16) * NHW + p0;
#pragma unroll
    for (int d = 0; d < 16; ++d) {
        *reinterpret_cast<float4*>(yb + (size_t)d * NHW) = Aa[d];
        *reinterpret_cast<float4*>(yb + (size_t)d * NHW + 256) = Ab[d];
    }

    float* ps = pooledsum + b * NCR + dg * 16;
#pragma unroll
    for (int d = 0; d < 16; ++d) {
        float s = Aa[d].x + Aa[d].y + Aa[d].z + Aa[d].w
                + Ab[d].x + Ab[d].y + Ab[d].z + Ab[d].w;
#pragma unroll
        for (int o = 32; o > 0; o >>= 1) s += __shfl_down(s, o, 64);
        if (lane == 0) atomicAdd(&ps[d], s);
    }
}

// K2: gamma[b,d] = sigmoid(relu(mean@w1^T+b1)@w2^T+b2); pooledsum -> mean
__global__ __launch_bounds__(512) void k_gate(const float* __restrict__ pooledsum,
                                              const float* __restrict__ w1,
                                              const float* __restrict__ b1,
                                              const float* __restrict__ w2,
                                              const float* __restrict__ b2,
                                              float* __restrict__ gamma) {
    __shared__ float hsh[NB][16];
    const int t = threadIdx.x;
    constexpr float inv = 1.f / (float)NHW;
    if (t < NB * 16) {
        const int b = t / 16, j = t % 16;
        float s = b1[j];
        for (int d = 0; d < NCR; ++d)
            s = fmaf(pooledsum[b * NCR + d] * inv, w1[j * NCR + d], s);
        hsh[b][j] = fmaxf(s, 0.f);
    }
    __syncthreads();
    const int b = t / NCR, d = t % NCR;
    float s = b2[d];
#pragma unroll
    for (int j = 0; j < 16; ++j) s = fmaf(hsh[b][j], w2[d * 16 + j], s);
    gamma[t] = 1.f / (1.f + expf(-s));
}

// K3a: per (b, 32x8 tile): stencil on y -> kappa -> logits -> m = 1+sigmoid
__global__ __launch_bounds__(256) void k_logits(const float* __restrict__ y,
                                                const float* __restrict__ gamma,
                                                const float* __restrict__ fw,
                                                float* __restrict__ m) {
    __shared__ float tile[TH + 2][TW + 2];           // 10 x 34
    __shared__ float coef[NCR];

    const int b = blockIdx.z;
    const int w0 = blockIdx.x * TW, h0 = blockIdx.y * TH;
    const int t = threadIdx.x;
    const int tx = t % TW, ty = t / TW;

    if (t < NCR) coef[t] = fw[t] + gamma[b * NCR + t] * fw[NCR + t];
    __syncthreads();

    const float* yb = y + (size_t)b * NCR * NHW;
    float logit = 0.f;

    for (int c = 0; c < NCR; ++c) {
        const float* yc = yb + (size_t)c * NHW;
        for (int i = t; i < (TH + 2) * (TW + 2); i += 256) {
            const int iy = i / (TW + 2), ix = i % (TW + 2);
            const int gh = h0 + iy - 1, gw = w0 + ix - 1;
            float v = 0.f;
            if (gh >= 0 && gh < NH && gw >= 0 && gw < NW) v = yc[gh * NW + gw];
            tile[iy][ix] = v;
        }
        __syncthreads();

        const float a00 = tile[ty][tx],     a01 = tile[ty][tx + 1],     a02 = tile[ty][tx + 2];
        const float a10 = tile[ty + 1][tx], a11 = tile[ty + 1][tx + 1], a12 = tile[ty + 1][tx + 2];
        const float a20 = tile[ty + 2][tx], a21 = tile[ty + 2][tx + 1], a22 = tile[ty + 2][tx + 2];

        const float mu = (a00 + a01 + a02 + a10 + a11 + a12 + a20 + a21 + a22) * (1.f / 9.f);
        const float gx = (a00 - a02 + 2.f * (a10 - a12) + a20 - a22) * 0.125f;
        const float gy = (a00 + 2.f * a01 + a02 - a20 - 2.f * a21 - a22) * 0.125f;
        const float kappa = 1.f - fabsf(a11 - mu) / (fabsf(gx) + fabsf(gy) + KEPS);
        logit = fmaf(kappa, coef[c], logit);
        __syncthreads();
    }

    const float a = 1.f / (1.f + expf(-logit));
    m[(size_t)b * NHW + (h0 + ty) * NW + (w0 + tx)] = 1.f + a;
}

// K3b: pure stream out = x * m. Block: 256 thr over 1024 px; 4 channels each.
__global__ __launch_bounds__(256) void k_mul(const float* __restrict__ x,
                                             const float* __restrict__ m,
                                             float* __restrict__ out) {
    const int b = blockIdx.z;
    const int c0 = blockIdx.y * 4;
    const int p = blockIdx.x * 1024 + threadIdx.x * 4;

    const float4 mv = *reinterpret_cast<const float4*>(m + (size_t)b * NHW + p);
    const size_t base = (size_t)b * NC * NHW + (size_t)c0 * NHW + p;
    const float* xp = x + base;
    float* op = out + base;

#pragma unroll
    for (int cc = 0; cc < 4; ++cc) {
        const float4 v = *reinterpret_cast<const float4*>(xp + (size_t)cc * NHW);
        float4 r;
        r.x = v.x * mv.x; r.y = v.y * mv.y; r.z = v.z * mv.z; r.w = v.w * mv.w;
        *reinterpret_cast<float4*>(op + (size_t)cc * NHW) = r;
    }
}

extern "C" void kernel_launch(void* const* d_in, const int* in_sizes, int n_in,
                              void* d_out, int out_size, void* d_ws, size_t ws_size,
                              hipStream_t stream) {
    const float* x  = (const float*)d_in[0];
    const float* rw = (const float*)d_in[1];
    const float* w1 = (const float*)d_in[2];
    const float* b1 = (const float*)d_in[3];
    const float* w2 = (const float*)d_in[4];
    const float* b2 = (const float*)d_in[5];
    const float* fw = (const float*)d_in[6];
    float* out = (float*)d_out;

    float* y      = (float*)d_ws;                       // 13,107,200 floats
    float* pooled = y + (size_t)NB * NCR * NHW;         // 512 floats (sums)
    float* gamma  = pooled + NB * NCR;                  // 512 floats
    float* rwT    = gamma + NB * NCR;                   // 16384 floats
    float* m      = rwT + NC * NCR;                     // 204800 floats

    k_tr<<<dim3(64), 256, 0, stream>>>(rw, rwT, pooled);
    k_reduce<<<dim3(NHW / 512, NB), 256, 0, stream>>>(x, rwT, y, pooled);
    k_gate<<<dim3(1), 512, 0, stream>>>(pooled, w1, b1, w2, b2, gamma);
    k_logits<<<dim3(NW / TW, NH / TH, NB), 256, 0, stream>>>(y, gamma, fw, m);
    k_mul<<<dim3(NHW / 1024, NC / 4, NB), 256, 0, stream>>>(x, m, out);
}